// Round 14
// baseline (409.181 us; speedup 1.0000x reference)
//
#include <hip/hip_runtime.h>
#include <hip/hip_bf16.h>
#include <math.h>

typedef unsigned short u16;
typedef unsigned int u32;
typedef unsigned long long u64;
typedef short s16x8 __attribute__((ext_vector_type(8)));
typedef u16 u16x8 __attribute__((ext_vector_type(8)));
typedef u32 u32x2 __attribute__((ext_vector_type(2)));
typedef u32 u32x4 __attribute__((ext_vector_type(4)));
typedef float f32x4 __attribute__((ext_vector_type(4)));

// Problem constants
#define TTOK 2048
#define HDIM 2048
#define ENUM 32
#define IDIM 768
#define KTOP 4

// Workspace layout (bytes)
#define WS_XB   0L                          // 8 MB bf16 x
#define WS_ACT  8388608L                    // 12.6 MB bf16 act
#define WS_TIDX 20971520L
#define WS_TW   (WS_TIDX + 32768L)
#define WS_CNT  (WS_TW + 32768L)
#define WS_OFFS (WS_CNT + 128L)
#define WS_CUR  (WS_OFFS + 256L)
#define WS_RTOK (WS_CUR + 128L)
#define WS_RW   (WS_RTOK + 32768L)
#define WS_RMAP (WS_RW + 32768L)            // int[8192] (tok,slot) -> row
#define WS_EO   25165824L                   // 32 MB scratch: g/u panels, then eo
#define WS_GBUF WS_EO                       // u16[8192*768]  (12.58 MB)
#define WS_UBUF (WS_EO + 12582912L)         // u16[8192*768]
#define WS_NEED (WS_EO + 33554432L)

#define LDBW 20   // B LDS row stride in dwords

__device__ __forceinline__ u16 f2bf(float f) {
  unsigned u = __builtin_bit_cast(unsigned, f);
  unsigned r = (u + 0x7fffu + ((u >> 16) & 1u)) >> 16;
  return (u16)r;
}

__device__ __forceinline__ u32 cvtpk(float lo, float hi) {
  u32 r;
  asm("v_cvt_pk_bf16_f32 %0, %1, %2" : "=v"(r) : "v"(lo), "v"(hi));
  return r;
}

__device__ __forceinline__ void gll16(const void* g, void* l) {
  u32 loff = __builtin_amdgcn_readfirstlane((u32)(u64)l);
  __builtin_amdgcn_global_load_lds(
      (const __attribute__((address_space(1))) u32*)(u64)g,
      (__attribute__((address_space(3))) u32*)loff, 16, 0, 0);
}

__device__ __forceinline__ s16x8 bfrag(const u32* B, int d0, int d1) {
  u32x2 lo = *(const u32x2*)(B + d0);
  u32x2 hi = *(const u32x2*)(B + d1);
  u32x4 v = {lo.x, lo.y, hi.x, hi.y};
  return __builtin_bit_cast(s16x8, v);
}

// ---------------- router (also emits xb = bf16(x)) ----------------
__global__ __launch_bounds__(256) void router_kernel(const float* __restrict__ x,
                                                     const float* __restrict__ gw,
                                                     u16* __restrict__ xb,
                                                     int* __restrict__ tidx,
                                                     float* __restrict__ tw,
                                                     int* __restrict__ counts) {
  __shared__ float xs[HDIM];
  __shared__ float part[256];
  __shared__ float lg[ENUM];
  int t = blockIdx.x;
  const float4* xr = (const float4*)(x + (long)t * HDIM);
  float4* xs4 = (float4*)xs;
  for (int i = threadIdx.x; i < HDIM / 4; i += 256) xs4[i] = xr[i];
  __syncthreads();
  {
    int i0 = threadIdx.x * 8;
    uint4 o;
    o.x = cvtpk(xs[i0], xs[i0 + 1]);
    o.y = cvtpk(xs[i0 + 2], xs[i0 + 3]);
    o.z = cvtpk(xs[i0 + 4], xs[i0 + 5]);
    o.w = cvtpk(xs[i0 + 6], xs[i0 + 7]);
    *(uint4*)(xb + (long)t * HDIM + i0) = o;
  }
  int e = threadIdx.x >> 3, ch = threadIdx.x & 7;
  const float4* gp = (const float4*)(gw + (long)e * HDIM + ch * 256);
  const float4* xp = (const float4*)(xs + ch * 256);
  float s = 0.f;
#pragma unroll 8
  for (int c = 0; c < 64; c++) {
    float4 gv = gp[c], xv = xp[c];
    s += gv.x * xv.x + gv.y * xv.y + gv.z * xv.z + gv.w * xv.w;
  }
  part[threadIdx.x] = s;
  __syncthreads();
  if (threadIdx.x < 32) {
    float v = 0.f;
#pragma unroll
    for (int j = 0; j < 8; j++) v += part[threadIdx.x * 8 + j];
    lg[threadIdx.x] = v;
  }
  __syncthreads();
  if (threadIdx.x == 0) {
    int sel[KTOP]; float sv[KTOP];
    unsigned mask = 0;
    for (int k = 0; k < KTOP; k++) {
      float best = -INFINITY; int bi = 0;
      for (int j = 0; j < ENUM; j++)
        if (!((mask >> j) & 1u) && lg[j] > best) { best = lg[j]; bi = j; }
      mask |= 1u << bi; sel[k] = bi; sv[k] = best;
    }
    float m = sv[0], den = 0.f, ex[KTOP];
    for (int k = 0; k < KTOP; k++) { ex[k] = expf(sv[k] - m); den += ex[k]; }
    for (int k = 0; k < KTOP; k++) {
      tidx[t * KTOP + k] = sel[k];
      tw[t * KTOP + k] = ex[k] / den;
      atomicAdd(&counts[sel[k]], 1);
    }
  }
}

// ---------------- scan ----------------
__global__ void scan_kernel(const int* __restrict__ counts, int* __restrict__ offs,
                            int* __restrict__ cur) {
  if (threadIdx.x == 0) {
    int a = 0;
    for (int e = 0; e < ENUM; e++) { offs[e] = a; a += counts[e]; }
    offs[ENUM] = a;
  }
  if (threadIdx.x < ENUM) cur[threadIdx.x] = 0;
}

// ---------------- scatter ----------------
__global__ __launch_bounds__(256) void scatter_kernel(const int* __restrict__ tidx,
                                                      const float* __restrict__ tw,
                                                      const int* __restrict__ offs,
                                                      int* __restrict__ cur,
                                                      int* __restrict__ rtok,
                                                      float* __restrict__ rw,
                                                      int* __restrict__ rowmap) {
  int i = blockIdx.x * 256 + threadIdx.x;
  int e = tidx[i];
  int pos = atomicAdd(&cur[e], 1);
  int row = offs[e] + pos;
  rtok[row] = i >> 2;
  rw[row] = tw[i];
  rowmap[i] = row;
}

// ================= GEMM1-split: one matrix (gate OR up) per block =================
// BM=256, BN=64, BK=32, 512 thr. 768 active blocks (2 mats x 12 nt x 32 e)
// -> 3 blocks/CU co-residency (43 KB LDS). Writes raw bf16 panel to g/u buf.
__global__ __launch_bounds__(512) void gemm1s_kernel(const u16* __restrict__ xb,
                                                     const float* __restrict__ wgp,
                                                     const float* __restrict__ wup,
                                                     const int* __restrict__ offs,
                                                     const int* __restrict__ rtok,
                                                     u16* __restrict__ gbuf,
                                                     u16* __restrict__ ubuf) {
  int d = blockIdx.x;
  int g = d % 768;
  int mt = d / 768;
  int e = g / 24;
  int r24 = g % 24;
  int nt = r24 >> 1;
  int mat = r24 & 1;
  int off = offs[e], cnt = offs[e + 1] - off;
  int m0 = mt << 8;
  if (m0 >= cnt) return;
  int rows = cnt - m0; if (rows > 256) rows = 256;
  int baser = off + m0;
  int n0 = nt << 6;

  __shared__ __align__(16) u16 As[2][256 * 32];    // 32 KB
  __shared__ __align__(16) u32 Bs[2][64 * LDBW];   // 10 KB

  int tid = threadIdx.x;
  int ln = tid & 63, w = tid >> 6;
  int wm = w >> 1, wn = w & 1;
  int lhi = ln >> 4, llo = ln & 15;

  const u16* gA[2];
  int ldsA[2];
#pragma unroll
  for (int j = 0; j < 2; j++) {
    int idx = w * 2 + j;
    int r = idx * 16 + (ln >> 2);
    int c = ln & 3;
    int csrc = c ^ ((r >> 1) & 3);
    int rr = r < rows ? r : rows - 1;
    gA[j] = xb + (long)rtok[baser + rr] * HDIM + csrc * 8;
    ldsA[j] = idx * 1024;
  }

  int isB = (tid < 256);
  int a = tid & 15;
  int kk = (tid >> 4) & 15;
  const float* gB = (mat ? wup : wgp) + (long)e * ((long)HDIM * IDIM) +
                    (long)(2 * kk) * IDIM + n0 + 4 * a;
  int fB = 2 * (a & 7);
  int wOff[4];
#pragma unroll
  for (int j = 0; j < 4; j++) wOff[j] = (4 * a + j) * LDBW + (kk ^ fB);

  int offA[4];
#pragma unroll
  for (int mf = 0; mf < 4; mf++) {
    int r = wm * 64 + mf * 16 + llo;
    offA[mf] = r * 64 + ((lhi ^ ((r >> 1) & 3)) * 16);
  }
  int dB0[2], dB1[2];
#pragma unroll
  for (int nf = 0; nf < 2; nf++) {
    int n = wn * 32 + nf * 16 + llo;
    int f = 2 * ((n >> 2) & 7);
    dB0[nf] = n * LDBW + ((4 * lhi) ^ f);
    dB1[nf] = n * LDBW + (((4 * lhi) | 2) ^ f);
  }

  f32x4 acc[4][2];
  f32x4 zz = {0.f, 0.f, 0.f, 0.f};
#pragma unroll
  for (int i = 0; i < 4; i++)
#pragma unroll
    for (int j = 0; j < 2; j++) acc[i][j] = zz;

  float4 rB0, rB1;

  if (isB) {
    rB0 = *(const float4*)gB;
    rB1 = *(const float4*)(gB + IDIM);
  }
  gll16(gA[0], (char*)As[0] + ldsA[0]);
  gll16(gA[1], (char*)As[0] + ldsA[1]);
  if (isB) {
    u32* bb = &Bs[0][0];
    bb[wOff[0]] = cvtpk(rB0.x, rB1.x);
    bb[wOff[1]] = cvtpk(rB0.y, rB1.y);
    bb[wOff[2]] = cvtpk(rB0.z, rB1.z);
    bb[wOff[3]] = cvtpk(rB0.w, rB1.w);
  }
  __syncthreads();

  const int NS = HDIM / 32;  // 64
  int buf = 0;
  for (int t = 0; t < NS; ++t) {
    if (t + 1 < NS) {
      if (isB) {
        const float* p = gB + (long)(t + 1) * 32 * IDIM;
        rB0 = *(const float4*)p;
        rB1 = *(const float4*)(p + IDIM);
      }
      gll16(gA[0] + (t + 1) * 32, (char*)As[buf ^ 1] + ldsA[0]);
      gll16(gA[1] + (t + 1) * 32, (char*)As[buf ^ 1] + ldsA[1]);
    }
    __builtin_amdgcn_sched_barrier(0);
    {
      const char* Ab = (const char*)As[buf];
      const u32* Bb = &Bs[buf][0];
      s16x8 av[4];
#pragma unroll
      for (int mf = 0; mf < 4; mf++) av[mf] = *(const s16x8*)(Ab + offA[mf]);
#pragma unroll
      for (int nf = 0; nf < 2; nf++) {
        s16x8 bv = bfrag(Bb, dB0[nf], dB1[nf]);
#pragma unroll
        for (int mf = 0; mf < 4; mf++)
          acc[mf][nf] = __builtin_amdgcn_mfma_f32_16x16x32_bf16(av[mf], bv, acc[mf][nf], 0, 0, 0);
      }
    }
    if (t + 1 < NS && isB) {
      u32* bb = &Bs[buf ^ 1][0];
      bb[wOff[0]] = cvtpk(rB0.x, rB1.x);
      bb[wOff[1]] = cvtpk(rB0.y, rB1.y);
      bb[wOff[2]] = cvtpk(rB0.z, rB1.z);
      bb[wOff[3]] = cvtpk(rB0.w, rB1.w);
    }
    __syncthreads();
    buf ^= 1;
  }

  // epilogue: raw bf16 panel store (silu applied in fuse kernel)
  u16* ob = mat ? ubuf : gbuf;
  int rb = wm * 64 + lhi * 4;
  int cb = n0 + wn * 32 + llo;
#pragma unroll
  for (int mf = 0; mf < 4; mf++) {
#pragma unroll
    for (int r4 = 0; r4 < 4; r4++) {
      int rl = rb + mf * 16 + r4;
      if (rl < rows) {
        long rowb = (long)(baser + rl) * IDIM;
#pragma unroll
        for (int nf = 0; nf < 2; nf++)
          ob[rowb + cb + nf * 16] = f2bf(acc[mf][nf][r4]);
      }
    }
  }
}

// ---------------- fuse: act = silu(g) * u ----------------
__global__ __launch_bounds__(256) void fuse_kernel(const u16* __restrict__ gbuf,
                                                   const u16* __restrict__ ubuf,
                                                   u16* __restrict__ act) {
  long i = ((long)blockIdx.x * 256 + threadIdx.x) * 8;
  u16x8 gv = *(const u16x8*)(gbuf + i);
  u16x8 uv = *(const u16x8*)(ubuf + i);
  u16x8 o;
#pragma unroll
  for (int j = 0; j < 8; j++) {
    float g = __builtin_bit_cast(float, ((u32)gv[j]) << 16);
    float u = __builtin_bit_cast(float, ((u32)uv[j]) << 16);
    o[j] = f2bf(g / (1.f + __expf(-g)) * u);
  }
  *(u16x8*)(act + i) = o;
}

// ================= GEMM1 fused (fallback when ws too small) =================
__global__ __launch_bounds__(512) void gemm1f_kernel(const u16* __restrict__ xb,
                                                     const float* __restrict__ wgp,
                                                     const float* __restrict__ wup,
                                                     const int* __restrict__ offs,
                                                     const int* __restrict__ rtok,
                                                     u16* __restrict__ act) {
  int d = blockIdx.x;
  int g = d % 384;
  int mt = d / 384;
  int e = g / 12;
  int nt = g % 12;
  int off = offs[e], cnt = offs[e + 1] - off;
  int m0 = mt << 8;
  if (m0 >= cnt) return;
  int rows = cnt - m0; if (rows > 256) rows = 256;
  int baser = off + m0;
  int n0 = nt << 6;

  __shared__ __align__(16) u16 As[2][256 * 32];
  __shared__ __align__(16) u32 Bs[2][2][64 * LDBW];

  int tid = threadIdx.x;
  int ln = tid & 63, w = tid >> 6;
  int wm = w >> 1, wn = w & 1;
  int lhi = ln >> 4, llo = ln & 15;

  const u16* gA[2];
  int ldsA[2];
#pragma unroll
  for (int j = 0; j < 2; j++) {
    int idx = w * 2 + j;
    int r = idx * 16 + (ln >> 2);
    int c = ln & 3;
    int csrc = c ^ ((r >> 1) & 3);
    int rr = r < rows ? r : rows - 1;
    gA[j] = xb + (long)rtok[baser + rr] * HDIM + csrc * 8;
    ldsA[j] = idx * 1024;
  }

  int mat = tid >> 8;
  int t2 = tid & 255;
  int a = t2 & 15;
  int kk = t2 >> 4;
  const float* gB = (mat ? wup : wgp) + (long)e * ((long)HDIM * IDIM) +
                    (long)(2 * kk) * IDIM + n0 + 4 * a;
  int fB = 2 * (a & 7);
  int wOff[4];
#pragma unroll
  for (int j = 0; j < 4; j++) wOff[j] = (4 * a + j) * LDBW + (kk ^ fB);

  int offA[4];
#pragma unroll
  for (int mf = 0; mf < 4; mf++) {
    int r = wm * 64 + mf * 16 + llo;
    offA[mf] = r * 64 + ((lhi ^ ((r >> 1) & 3)) * 16);
  }
  int dB0[2], dB1[2];
#pragma unroll
  for (int nf = 0; nf < 2; nf++) {
    int n = wn * 32 + nf * 16 + llo;
    int f = 2 * ((n >> 2) & 7);
    dB0[nf] = n * LDBW + ((4 * lhi) ^ f);
    dB1[nf] = n * LDBW + (((4 * lhi) | 2) ^ f);
  }

  f32x4 accg[4][2], accu[4][2];
  f32x4 zz = {0.f, 0.f, 0.f, 0.f};
#pragma unroll
  for (int i = 0; i < 4; i++)
#pragma unroll
    for (int j = 0; j < 2; j++) { accg[i][j] = zz; accu[i][j] = zz; }

  float4 rB0, rB1;

  rB0 = *(const float4*)gB;
  rB1 = *(const float4*)(gB + IDIM);
  gll16(gA[0], (char*)As[0] + ldsA[0]);
  gll16(gA[1], (char*)As[0] + ldsA[1]);
  {
    u32* bb = &Bs[0][mat][0];
    bb[wOff[0]] = cvtpk(rB0.x, rB1.x);
    bb[wOff[1]] = cvtpk(rB0.y, rB1.y);
    bb[wOff[2]] = cvtpk(rB0.z, rB1.z);
    bb[wOff[3]] = cvtpk(rB0.w, rB1.w);
  }
  __syncthreads();

  const int NS = HDIM / 32;
  int buf = 0;
  for (int t = 0; t < NS; ++t) {
    if (t + 1 < NS) {
      const float* p = gB + (long)(t + 1) * 32 * IDIM;
      rB0 = *(const float4*)p;
      rB1 = *(const float4*)(p + IDIM);
      gll16(gA[0] + (t + 1) * 32, (char*)As[buf ^ 1] + ldsA[0]);
      gll16(gA[1] + (t + 1) * 32, (char*)As[buf ^ 1] + ldsA[1]);
    }
    __builtin_amdgcn_sched_barrier(0);
    {
      const char* Ab = (const char*)As[buf];
      const u32* Bg = &Bs[buf][0][0];
      const u32* Bu = &Bs[buf][1][0];
      s16x8 av[4];
#pragma unroll
      for (int mf = 0; mf < 4; mf++) av[mf] = *(const s16x8*)(Ab + offA[mf]);
#pragma unroll
      for (int nf = 0; nf < 2; nf++) {
        s16x8 bg = bfrag(Bg, dB0[nf], dB1[nf]);
        s16x8 bu = bfrag(Bu, dB0[nf], dB1[nf]);
#pragma unroll
        for (int mf = 0; mf < 4; mf++) {
          accg[mf][nf] = __builtin_amdgcn_mfma_f32_16x16x32_bf16(av[mf], bg, accg[mf][nf], 0, 0, 0);
          accu[mf][nf] = __builtin_amdgcn_mfma_f32_16x16x32_bf16(av[mf], bu, accu[mf][nf], 0, 0, 0);
        }
      }
    }
    if (t + 1 < NS) {
      u32* bb = &Bs[buf ^ 1][mat][0];
      bb[wOff[0]] = cvtpk(rB0.x, rB1.x);
      bb[wOff[1]] = cvtpk(rB0.y, rB1.y);
      bb[wOff[2]] = cvtpk(rB0.z, rB1.z);
      bb[wOff[3]] = cvtpk(rB0.w, rB1.w);
    }
    __syncthreads();
    buf ^= 1;
  }

  int rb = wm * 64 + lhi * 4;
  int cb = n0 + wn * 32 + llo;
#pragma unroll
  for (int mf = 0; mf < 4; mf++) {
#pragma unroll
    for (int r4 = 0; r4 < 4; r4++) {
      int rl = rb + mf * 16 + r4;
      if (rl < rows) {
        long rowb = (long)(baser + rl) * IDIM;
#pragma unroll
        for (int nf = 0; nf < 2; nf++) {
          float g2 = accg[mf][nf][r4], u = accu[mf][nf][r4];
          float av = g2 / (1.f + __expf(-g2)) * u;
          act[rowb + cb + nf * 16] = f2bf(av);
        }
      }
    }
  }
}

// ================= GEMM2: BN=128; expert-grouped dispatch map =================
template <int STORE>
__global__ __launch_bounds__(512) void gemm2_kernel(const u16* __restrict__ act,
                                                    const float* __restrict__ wdp,
                                                    const int* __restrict__ offs,
                                                    const int* __restrict__ rtok,
                                                    const float* __restrict__ rw,
                                                    u16* __restrict__ eo,
                                                    float* __restrict__ out) {
  int d = blockIdx.x;
  int g = d & 511;
  int mt = d >> 9;
  int e = g >> 4;
  int nt = g & 15;
  int off = offs[e], cnt = offs[e + 1] - off;
  int m0 = mt << 8;
  if (m0 >= cnt) return;
  int rows = cnt - m0; if (rows > 256) rows = 256;
  int baser = off + m0;
  int n0 = nt << 7;

  __shared__ __align__(16) u16 As[2][256 * 32];     // 32 KB
  __shared__ __align__(16) u32 Bs[2][128 * LDBW];   // 20 KB

  int tid = threadIdx.x;
  int ln = tid & 63, w = tid >> 6;
  int wm = w >> 1, wn = w & 1;
  int lhi = ln >> 4, llo = ln & 15;

  const u16* gA[2];
  int ldsA[2];
#pragma unroll
  for (int j = 0; j < 2; j++) {
    int idx = w * 2 + j;
    int r = idx * 16 + (ln >> 2);
    int c = ln & 3;
    int csrc = c ^ ((r >> 1) & 3);
    int rr = r < rows ? r : rows - 1;
    gA[j] = act + (long)(baser + rr) * IDIM + csrc * 8;
    ldsA[j] = idx * 1024;
  }

  int a = tid & 31;
  int kk = (tid >> 5) & 15;
  const float* gB = wdp + (long)e * ((long)IDIM * HDIM) +
                    (long)(2 * kk) * HDIM + n0 + 4 * a;
  int fB = 2 * (a & 7);
  int wOff[4];
#pragma unroll
  for (int j = 0; j < 4; j++) wOff[j] = (4 * a + j) * LDBW + (kk ^ fB);

  int offA[4];
#pragma unroll
  for (int mf = 0; mf < 4; mf++) {
    int r = wm * 64 + mf * 16 + llo;
    offA[mf] = r * 64 + ((lhi ^ ((r >> 1) & 3)) * 16);
  }
  int dB0[4], dB1[4];
#pragma unroll
  for (int nf = 0; nf < 4; nf++) {
    int n = wn * 64 + nf * 16 + llo;
    int f = 2 * ((n >> 2) & 7);
    dB0[nf] = n * LDBW + ((4 * lhi) ^ f);
    dB1[nf] = n * LDBW + (((4 * lhi) | 2) ^ f);
  }

  f32x4 acc[4][4];
  f32x4 zz = {0.f, 0.f, 0.f, 0.f};
#pragma unroll
  for (int i = 0; i < 4; i++)
#pragma unroll
    for (int j = 0; j < 4; j++) acc[i][j] = zz;

  float4 rB0, rB1;

  rB0 = *(const float4*)gB;
  rB1 = *(const float4*)(gB + HDIM);
  gll16(gA[0], (char*)As[0] + ldsA[0]);
  gll16(gA[1], (char*)As[0] + ldsA[1]);
  {
    u32* bb = &Bs[0][0];
    bb[wOff[0]] = cvtpk(rB0.x, rB1.x);
    bb[wOff[1]] = cvtpk(rB0.y, rB1.y);
    bb[wOff[2]] = cvtpk(rB0.z, rB1.z);
    bb[wOff[3]] = cvtpk(rB0.w, rB1.w);
  }
  __syncthreads();

  const int NS = IDIM / 32;  // 24
  int buf = 0;
  for (int t = 0; t < NS; ++t) {
    if (t + 1 < NS) {
      const float* p = gB + (long)(t + 1) * 32 * HDIM;
      rB0 = *(const float4*)p;
      rB1 = *(const float4*)(p + HDIM);
      gll16(gA[0] + (t + 1) * 32, (char*)As[buf ^ 1] + ldsA[0]);
      gll16(gA[1] + (t + 1) * 32, (char*)As[buf ^ 1] + ldsA[1]);
    }
    __builtin_amdgcn_sched_barrier(0);
    {
      const char* Ab = (const char*)As[buf];
      const u32* Bb = &Bs[buf][0];
      s16x8 av[4];
#pragma unroll
      for (int mf = 0; mf < 4; mf++) av[mf] = *(const s16x8*)(Ab + offA[mf]);
#pragma unroll
      for (int nf = 0; nf < 4; nf++) {
        s16x8 bv = bfrag(Bb, dB0[nf], dB1[nf]);
#pragma unroll
        for (int mf = 0; mf < 4; mf++)
          acc[mf][nf] = __builtin_amdgcn_mfma_f32_16x16x32_bf16(av[mf], bv, acc[mf][nf], 0, 0, 0);
      }
    }
    if (t + 1 < NS) {
      u32* bb = &Bs[buf ^ 1][0];
      bb[wOff[0]] = cvtpk(rB0.x, rB1.x);
      bb[wOff[1]] = cvtpk(rB0.y, rB1.y);
      bb[wOff[2]] = cvtpk(rB0.z, rB1.z);
      bb[wOff[3]] = cvtpk(rB0.w, rB1.w);
    }
    __syncthreads();
    buf ^= 1;
  }

  int rb = wm * 64 + lhi * 4;
  int cb = n0 + wn * 64 + llo;
#pragma unroll
  for (int mf = 0; mf < 4; mf++) {
#pragma unroll
    for (int r4 = 0; r4 < 4; r4++) {
      int rl = rb + mf * 16 + r4;
      if (rl < rows) {
        int rr = baser + rl;
        if (STORE) {
          long ob = (long)rr * HDIM + cb;
#pragma unroll
          for (int nf = 0; nf < 4; nf++)
            eo[ob + nf * 16] = f2bf(acc[mf][nf][r4]);
        } else {
          float wt = rw[rr];
          long ob = (long)rtok[rr] * HDIM + cb;
#pragma unroll
          for (int nf = 0; nf < 4; nf++)
            atomicAdd(&out[ob + nf * 16], acc[mf][nf][r4] * wt);
        }
      }
    }
  }
}

// ---------------- combine: out[t] = sum_k tw[t,k] * eo[row(t,k)] ----------------
__global__ __launch_bounds__(256) void combine_kernel(const u16* __restrict__ eo,
                                                      const int* __restrict__ rowmap,
                                                      const float* __restrict__ tw,
                                                      float* __restrict__ out) {
  int t = blockIdx.x;
  int h0 = threadIdx.x * 8;
  float acc[8] = {0.f, 0.f, 0.f, 0.f, 0.f, 0.f, 0.f, 0.f};
#pragma unroll
  for (int k = 0; k < KTOP; k++) {
    int r = rowmap[t * KTOP + k];
    float wt = tw[t * KTOP + k];
    u16x8 v = *(const u16x8*)(eo + (long)r * HDIM + h0);
#pragma unroll
    for (int j = 0; j < 8; j++)
      acc[j] += wt * __builtin_bit_cast(float, ((u32)v[j]) << 16);
  }
  float4 o0 = {acc[0], acc[1], acc[2], acc[3]};
  float4 o1 = {acc[4], acc[5], acc[6], acc[7]};
  *(float4*)(out + (long)t * HDIM + h0) = o0;
  *(float4*)(out + (long)t * HDIM + h0 + 4) = o1;
}

extern "C" void kernel_launch(void* const* d_in, const int* in_sizes, int n_in,
                              void* d_out, int out_size, void* d_ws, size_t ws_size,
                              hipStream_t stream) {
  const float* x = (const float*)d_in[0];
  const float* gw = (const float*)d_in[1];
  const float* wgate = (const float*)d_in[2];
  const float* wup = (const float*)d_in[3];
  const float* wdown = (const float*)d_in[4];
  float* out = (float*)d_out;

  char* ws = (char*)d_ws;
  u16* xb = (u16*)(ws + WS_XB);
  u16* act = (u16*)(ws + WS_ACT);
  int* tidx = (int*)(ws + WS_TIDX);
  float* tw = (float*)(ws + WS_TW);
  int* cnt = (int*)(ws + WS_CNT);
  int* offs = (int*)(ws + WS_OFFS);
  int* cur = (int*)(ws + WS_CUR);
  int* rtok = (int*)(ws + WS_RTOK);
  float* rw = (float*)(ws + WS_RW);
  int* rowmap = (int*)(ws + WS_RMAP);
  u16* gbuf = (u16*)(ws + WS_GBUF);
  u16* ubuf = (u16*)(ws + WS_UBUF);
  u16* eo = (u16*)(ws + WS_EO);
  bool storeMode = (ws_size >= (size_t)WS_NEED);

  hipMemsetAsync(cnt, 0, 128, stream);
  if (!storeMode)
    hipMemsetAsync(d_out, 0, (size_t)out_size * sizeof(float), stream);

  hipLaunchKernelGGL(router_kernel, dim3(TTOK), dim3(256), 0, stream, x, gw, xb, tidx, tw, cnt);
  hipLaunchKernelGGL(scan_kernel, dim3(1), dim3(64), 0, stream, cnt, offs, cur);
  hipLaunchKernelGGL(scatter_kernel, dim3(TTOK * KTOP / 256), dim3(256), 0, stream, tidx, tw, offs, cur, rtok, rw, rowmap);
  if (storeMode) {
    hipLaunchKernelGGL(gemm1s_kernel, dim3(768 * 8), dim3(512), 0, stream, xb, wgate, wup, offs, rtok, gbuf, ubuf);
    hipLaunchKernelGGL(fuse_kernel, dim3(TTOK * KTOP * IDIM / (256 * 8)), dim3(256), 0, stream, gbuf, ubuf, act);
    hipLaunchKernelGGL(gemm2_kernel<1>, dim3(32 * 16 * 8), dim3(512), 0, stream, act, wdown, offs, rtok, rw, eo, out);
    hipLaunchKernelGGL(combine_kernel, dim3(TTOK), dim3(256), 0, stream, eo, rowmap, tw, out);
  } else {
    hipLaunchKernelGGL(gemm1f_kernel, dim3(32 * 12 * 8), dim3(512), 0, stream, xb, wgate, wup, offs, rtok, act);
    hipLaunchKernelGGL(gemm2_kernel<0>, dim3(32 * 16 * 8), dim3(512), 0, stream, act, wdown, offs, rtok, rw, eo, out);
  }
}

// Round 15
// 369.734 us; speedup vs baseline: 1.1067x; 1.1067x over previous
//
#include <hip/hip_runtime.h>
#include <hip/hip_bf16.h>
#include <math.h>

typedef unsigned short u16;
typedef unsigned int u32;
typedef unsigned long long u64;
typedef short s16x8 __attribute__((ext_vector_type(8)));
typedef u16 u16x8 __attribute__((ext_vector_type(8)));
typedef u32 u32x2 __attribute__((ext_vector_type(2)));
typedef u32 u32x4 __attribute__((ext_vector_type(4)));
typedef float f32x4 __attribute__((ext_vector_type(4)));

// Problem constants
#define TTOK 2048
#define HDIM 2048
#define ENUM 32
#define IDIM 768
#define KTOP 4

// Workspace layout (bytes)
#define WS_XB   0L                          // 8 MB bf16 x
#define WS_ACT  8388608L                    // 12.6 MB bf16 act
#define WS_TIDX 20971520L
#define WS_TW   (WS_TIDX + 32768L)
#define WS_CNT  (WS_TW + 32768L)
#define WS_OFFS (WS_CNT + 128L)
#define WS_CUR  (WS_OFFS + 256L)
#define WS_RTOK (WS_CUR + 128L)
#define WS_RW   (WS_RTOK + 32768L)
#define WS_RMAP (WS_RW + 32768L)            // int[8192] (tok,slot) -> row
#define WS_EO   25165824L                   // 32 MB bf16 expert rows [8192][2048]
#define WS_NEED (WS_EO + 33554432L)

#define LDBW 20   // B LDS row stride in dwords

__device__ __forceinline__ u16 f2bf(float f) {
  unsigned u = __builtin_bit_cast(unsigned, f);
  unsigned r = (u + 0x7fffu + ((u >> 16) & 1u)) >> 16;
  return (u16)r;
}

__device__ __forceinline__ u32 cvtpk(float lo, float hi) {
  u32 r;
  asm("v_cvt_pk_bf16_f32 %0, %1, %2" : "=v"(r) : "v"(lo), "v"(hi));
  return r;
}

__device__ __forceinline__ void gll16(const void* g, void* l) {
  u32 loff = __builtin_amdgcn_readfirstlane((u32)(u64)l);
  __builtin_amdgcn_global_load_lds(
      (const __attribute__((address_space(1))) u32*)(u64)g,
      (__attribute__((address_space(3))) u32*)loff, 16, 0, 0);
}

__device__ __forceinline__ s16x8 bfrag(const u32* B, int d0, int d1) {
  u32x2 lo = *(const u32x2*)(B + d0);
  u32x2 hi = *(const u32x2*)(B + d1);
  u32x4 v = {lo.x, lo.y, hi.x, hi.y};
  return __builtin_bit_cast(s16x8, v);
}

// ---------------- router (also emits xb = bf16(x)) ----------------
__global__ __launch_bounds__(256) void router_kernel(const float* __restrict__ x,
                                                     const float* __restrict__ gw,
                                                     u16* __restrict__ xb,
                                                     int* __restrict__ tidx,
                                                     float* __restrict__ tw,
                                                     int* __restrict__ counts) {
  __shared__ float xs[HDIM];
  __shared__ float part[256];
  __shared__ float lg[ENUM];
  int t = blockIdx.x;
  const float4* xr = (const float4*)(x + (long)t * HDIM);
  float4* xs4 = (float4*)xs;
  for (int i = threadIdx.x; i < HDIM / 4; i += 256) xs4[i] = xr[i];
  __syncthreads();
  {
    int i0 = threadIdx.x * 8;
    uint4 o;
    o.x = cvtpk(xs[i0], xs[i0 + 1]);
    o.y = cvtpk(xs[i0 + 2], xs[i0 + 3]);
    o.z = cvtpk(xs[i0 + 4], xs[i0 + 5]);
    o.w = cvtpk(xs[i0 + 6], xs[i0 + 7]);
    *(uint4*)(xb + (long)t * HDIM + i0) = o;
  }
  int e = threadIdx.x >> 3, ch = threadIdx.x & 7;
  const float4* gp = (const float4*)(gw + (long)e * HDIM + ch * 256);
  const float4* xp = (const float4*)(xs + ch * 256);
  float s = 0.f;
#pragma unroll 8
  for (int c = 0; c < 64; c++) {
    float4 gv = gp[c], xv = xp[c];
    s += gv.x * xv.x + gv.y * xv.y + gv.z * xv.z + gv.w * xv.w;
  }
  part[threadIdx.x] = s;
  __syncthreads();
  if (threadIdx.x < 32) {
    float v = 0.f;
#pragma unroll
    for (int j = 0; j < 8; j++) v += part[threadIdx.x * 8 + j];
    lg[threadIdx.x] = v;
  }
  __syncthreads();
  if (threadIdx.x == 0) {
    int sel[KTOP]; float sv[KTOP];
    unsigned mask = 0;
    for (int k = 0; k < KTOP; k++) {
      float best = -INFINITY; int bi = 0;
      for (int j = 0; j < ENUM; j++)
        if (!((mask >> j) & 1u) && lg[j] > best) { best = lg[j]; bi = j; }
      mask |= 1u << bi; sel[k] = bi; sv[k] = best;
    }
    float m = sv[0], den = 0.f, ex[KTOP];
    for (int k = 0; k < KTOP; k++) { ex[k] = expf(sv[k] - m); den += ex[k]; }
    for (int k = 0; k < KTOP; k++) {
      tidx[t * KTOP + k] = sel[k];
      tw[t * KTOP + k] = ex[k] / den;
      atomicAdd(&counts[sel[k]], 1);
    }
  }
}

// ---------------- scan ----------------
__global__ void scan_kernel(const int* __restrict__ counts, int* __restrict__ offs,
                            int* __restrict__ cur) {
  if (threadIdx.x == 0) {
    int a = 0;
    for (int e = 0; e < ENUM; e++) { offs[e] = a; a += counts[e]; }
    offs[ENUM] = a;
  }
  if (threadIdx.x < ENUM) cur[threadIdx.x] = 0;
}

// ---------------- scatter ----------------
__global__ __launch_bounds__(256) void scatter_kernel(const int* __restrict__ tidx,
                                                      const float* __restrict__ tw,
                                                      const int* __restrict__ offs,
                                                      int* __restrict__ cur,
                                                      int* __restrict__ rtok,
                                                      float* __restrict__ rw,
                                                      int* __restrict__ rowmap) {
  int i = blockIdx.x * 256 + threadIdx.x;
  int e = tidx[i];
  int pos = atomicAdd(&cur[e], 1);
  int row = offs[e] + pos;
  rtok[row] = i >> 2;
  rw[row] = tw[i];
  rowmap[i] = row;
}

// ================= GEMM1: act = silu(x Wg) * (x Wu) =================
// Best measured (R13): BM=256, BN=64, BK=32, 512 thr, expert-grouped dispatch.
__global__ __launch_bounds__(512) void gemm1_kernel(const u16* __restrict__ xb,
                                                    const float* __restrict__ wgp,
                                                    const float* __restrict__ wup,
                                                    const int* __restrict__ offs,
                                                    const int* __restrict__ rtok,
                                                    u16* __restrict__ act) {
  int d = blockIdx.x;
  int g = d % 384;
  int mt = d / 384;
  int e = g / 12;
  int nt = g % 12;
  int off = offs[e], cnt = offs[e + 1] - off;
  int m0 = mt << 8;
  if (m0 >= cnt) return;
  int rows = cnt - m0; if (rows > 256) rows = 256;
  int baser = off + m0;
  int n0 = nt << 6;

  __shared__ __align__(16) u16 As[2][256 * 32];       // 32 KB
  __shared__ __align__(16) u32 Bs[2][2][64 * LDBW];   // 20 KB

  int tid = threadIdx.x;
  int ln = tid & 63, w = tid >> 6;
  int wm = w >> 1, wn = w & 1;
  int lhi = ln >> 4, llo = ln & 15;

  const u16* gA[2];
  int ldsA[2];
#pragma unroll
  for (int j = 0; j < 2; j++) {
    int idx = w * 2 + j;
    int r = idx * 16 + (ln >> 2);
    int c = ln & 3;
    int csrc = c ^ ((r >> 1) & 3);
    int rr = r < rows ? r : rows - 1;
    gA[j] = xb + (long)rtok[baser + rr] * HDIM + csrc * 8;
    ldsA[j] = idx * 1024;
  }

  int mat = tid >> 8;
  int t2 = tid & 255;
  int a = t2 & 15;
  int kk = t2 >> 4;
  const float* gB = (mat ? wup : wgp) + (long)e * ((long)HDIM * IDIM) +
                    (long)(2 * kk) * IDIM + n0 + 4 * a;
  int fB = 2 * (a & 7);
  int wOff[4];
#pragma unroll
  for (int j = 0; j < 4; j++) wOff[j] = (4 * a + j) * LDBW + (kk ^ fB);

  int offA[4];
#pragma unroll
  for (int mf = 0; mf < 4; mf++) {
    int r = wm * 64 + mf * 16 + llo;
    offA[mf] = r * 64 + ((lhi ^ ((r >> 1) & 3)) * 16);
  }
  int dB0[2], dB1[2];
#pragma unroll
  for (int nf = 0; nf < 2; nf++) {
    int n = wn * 32 + nf * 16 + llo;
    int f = 2 * ((n >> 2) & 7);
    dB0[nf] = n * LDBW + ((4 * lhi) ^ f);
    dB1[nf] = n * LDBW + (((4 * lhi) | 2) ^ f);
  }

  f32x4 accg[4][2], accu[4][2];
  f32x4 zz = {0.f, 0.f, 0.f, 0.f};
#pragma unroll
  for (int i = 0; i < 4; i++)
#pragma unroll
    for (int j = 0; j < 2; j++) { accg[i][j] = zz; accu[i][j] = zz; }

  float4 rB0, rB1;

  rB0 = *(const float4*)gB;
  rB1 = *(const float4*)(gB + IDIM);
  gll16(gA[0], (char*)As[0] + ldsA[0]);
  gll16(gA[1], (char*)As[0] + ldsA[1]);
  {
    u32* bb = &Bs[0][mat][0];
    bb[wOff[0]] = cvtpk(rB0.x, rB1.x);
    bb[wOff[1]] = cvtpk(rB0.y, rB1.y);
    bb[wOff[2]] = cvtpk(rB0.z, rB1.z);
    bb[wOff[3]] = cvtpk(rB0.w, rB1.w);
  }
  __syncthreads();

  const int NS = HDIM / 32;  // 64
  int buf = 0;
  for (int t = 0; t < NS; ++t) {
    if (t + 1 < NS) {
      const float* p = gB + (long)(t + 1) * 32 * IDIM;
      rB0 = *(const float4*)p;
      rB1 = *(const float4*)(p + IDIM);
      gll16(gA[0] + (t + 1) * 32, (char*)As[buf ^ 1] + ldsA[0]);
      gll16(gA[1] + (t + 1) * 32, (char*)As[buf ^ 1] + ldsA[1]);
    }
    __builtin_amdgcn_sched_barrier(0);
    {
      const char* Ab = (const char*)As[buf];
      const u32* Bg = &Bs[buf][0][0];
      const u32* Bu = &Bs[buf][1][0];
      s16x8 av[4];
#pragma unroll
      for (int mf = 0; mf < 4; mf++) av[mf] = *(const s16x8*)(Ab + offA[mf]);
#pragma unroll
      for (int nf = 0; nf < 2; nf++) {
        s16x8 bg = bfrag(Bg, dB0[nf], dB1[nf]);
        s16x8 bu = bfrag(Bu, dB0[nf], dB1[nf]);
#pragma unroll
        for (int mf = 0; mf < 4; mf++) {
          accg[mf][nf] = __builtin_amdgcn_mfma_f32_16x16x32_bf16(av[mf], bg, accg[mf][nf], 0, 0, 0);
          accu[mf][nf] = __builtin_amdgcn_mfma_f32_16x16x32_bf16(av[mf], bu, accu[mf][nf], 0, 0, 0);
        }
      }
    }
    if (t + 1 < NS) {
      u32* bb = &Bs[buf ^ 1][mat][0];
      bb[wOff[0]] = cvtpk(rB0.x, rB1.x);
      bb[wOff[1]] = cvtpk(rB0.y, rB1.y);
      bb[wOff[2]] = cvtpk(rB0.z, rB1.z);
      bb[wOff[3]] = cvtpk(rB0.w, rB1.w);
    }
    __syncthreads();
    buf ^= 1;
  }

  int rb = wm * 64 + lhi * 4;
  int cb = n0 + wn * 32 + llo;
#pragma unroll
  for (int mf = 0; mf < 4; mf++) {
#pragma unroll
    for (int r4 = 0; r4 < 4; r4++) {
      int rl = rb + mf * 16 + r4;
      if (rl < rows) {
        long rowb = (long)(baser + rl) * IDIM;
#pragma unroll
        for (int nf = 0; nf < 2; nf++) {
          float g2 = accg[mf][nf][r4], u = accu[mf][nf][r4];
          float av = g2 / (1.f + __expf(-g2)) * u;
          act[rowb + cb + nf * 16] = f2bf(av);
        }
      }
    }
  }
}

// ================= GEMM2: BN=128; expert-grouped dispatch map =================
template <int STORE>
__global__ __launch_bounds__(512) void gemm2_kernel(const u16* __restrict__ act,
                                                    const float* __restrict__ wdp,
                                                    const int* __restrict__ offs,
                                                    const int* __restrict__ rtok,
                                                    const float* __restrict__ rw,
                                                    u16* __restrict__ eo,
                                                    float* __restrict__ out) {
  int d = blockIdx.x;
  int g = d & 511;
  int mt = d >> 9;
  int e = g >> 4;
  int nt = g & 15;
  int off = offs[e], cnt = offs[e + 1] - off;
  int m0 = mt << 8;
  if (m0 >= cnt) return;
  int rows = cnt - m0; if (rows > 256) rows = 256;
  int baser = off + m0;
  int n0 = nt << 7;

  __shared__ __align__(16) u16 As[2][256 * 32];     // 32 KB
  __shared__ __align__(16) u32 Bs[2][128 * LDBW];   // 20 KB

  int tid = threadIdx.x;
  int ln = tid & 63, w = tid >> 6;
  int wm = w >> 1, wn = w & 1;
  int lhi = ln >> 4, llo = ln & 15;

  const u16* gA[2];
  int ldsA[2];
#pragma unroll
  for (int j = 0; j < 2; j++) {
    int idx = w * 2 + j;
    int r = idx * 16 + (ln >> 2);
    int c = ln & 3;
    int csrc = c ^ ((r >> 1) & 3);
    int rr = r < rows ? r : rows - 1;
    gA[j] = act + (long)(baser + rr) * IDIM + csrc * 8;
    ldsA[j] = idx * 1024;
  }

  int a = tid & 31;
  int kk = (tid >> 5) & 15;
  const float* gB = wdp + (long)e * ((long)IDIM * HDIM) +
                    (long)(2 * kk) * HDIM + n0 + 4 * a;
  int fB = 2 * (a & 7);
  int wOff[4];
#pragma unroll
  for (int j = 0; j < 4; j++) wOff[j] = (4 * a + j) * LDBW + (kk ^ fB);

  int offA[4];
#pragma unroll
  for (int mf = 0; mf < 4; mf++) {
    int r = wm * 64 + mf * 16 + llo;
    offA[mf] = r * 64 + ((lhi ^ ((r >> 1) & 3)) * 16);
  }
  int dB0[4], dB1[4];
#pragma unroll
  for (int nf = 0; nf < 4; nf++) {
    int n = wn * 64 + nf * 16 + llo;
    int f = 2 * ((n >> 2) & 7);
    dB0[nf] = n * LDBW + ((4 * lhi) ^ f);
    dB1[nf] = n * LDBW + (((4 * lhi) | 2) ^ f);
  }

  f32x4 acc[4][4];
  f32x4 zz = {0.f, 0.f, 0.f, 0.f};
#pragma unroll
  for (int i = 0; i < 4; i++)
#pragma unroll
    for (int j = 0; j < 4; j++) acc[i][j] = zz;

  float4 rB0, rB1;

  rB0 = *(const float4*)gB;
  rB1 = *(const float4*)(gB + HDIM);
  gll16(gA[0], (char*)As[0] + ldsA[0]);
  gll16(gA[1], (char*)As[0] + ldsA[1]);
  {
    u32* bb = &Bs[0][0];
    bb[wOff[0]] = cvtpk(rB0.x, rB1.x);
    bb[wOff[1]] = cvtpk(rB0.y, rB1.y);
    bb[wOff[2]] = cvtpk(rB0.z, rB1.z);
    bb[wOff[3]] = cvtpk(rB0.w, rB1.w);
  }
  __syncthreads();

  const int NS = IDIM / 32;  // 24
  int buf = 0;
  for (int t = 0; t < NS; ++t) {
    if (t + 1 < NS) {
      const float* p = gB + (long)(t + 1) * 32 * HDIM;
      rB0 = *(const float4*)p;
      rB1 = *(const float4*)(p + HDIM);
      gll16(gA[0] + (t + 1) * 32, (char*)As[buf ^ 1] + ldsA[0]);
      gll16(gA[1] + (t + 1) * 32, (char*)As[buf ^ 1] + ldsA[1]);
    }
    __builtin_amdgcn_sched_barrier(0);
    {
      const char* Ab = (const char*)As[buf];
      const u32* Bb = &Bs[buf][0];
      s16x8 av[4];
#pragma unroll
      for (int mf = 0; mf < 4; mf++) av[mf] = *(const s16x8*)(Ab + offA[mf]);
#pragma unroll
      for (int nf = 0; nf < 4; nf++) {
        s16x8 bv = bfrag(Bb, dB0[nf], dB1[nf]);
#pragma unroll
        for (int mf = 0; mf < 4; mf++)
          acc[mf][nf] = __builtin_amdgcn_mfma_f32_16x16x32_bf16(av[mf], bv, acc[mf][nf], 0, 0, 0);
      }
    }
    if (t + 1 < NS) {
      u32* bb = &Bs[buf ^ 1][0];
      bb[wOff[0]] = cvtpk(rB0.x, rB1.x);
      bb[wOff[1]] = cvtpk(rB0.y, rB1.y);
      bb[wOff[2]] = cvtpk(rB0.z, rB1.z);
      bb[wOff[3]] = cvtpk(rB0.w, rB1.w);
    }
    __syncthreads();
    buf ^= 1;
  }

  int rb = wm * 64 + lhi * 4;
  int cb = n0 + wn * 64 + llo;
#pragma unroll
  for (int mf = 0; mf < 4; mf++) {
#pragma unroll
    for (int r4 = 0; r4 < 4; r4++) {
      int rl = rb + mf * 16 + r4;
      if (rl < rows) {
        int rr = baser + rl;
        if (STORE) {
          long ob = (long)rr * HDIM + cb;
#pragma unroll
          for (int nf = 0; nf < 4; nf++)
            eo[ob + nf * 16] = f2bf(acc[mf][nf][r4]);
        } else {
          float wt = rw[rr];
          long ob = (long)rtok[rr] * HDIM + cb;
#pragma unroll
          for (int nf = 0; nf < 4; nf++)
            atomicAdd(&out[ob + nf * 16], acc[mf][nf][r4] * wt);
        }
      }
    }
  }
}

// ---------------- combine: out[t] = sum_k tw[t,k] * eo[row(t,k)] ----------------
__global__ __launch_bounds__(256) void combine_kernel(const u16* __restrict__ eo,
                                                      const int* __restrict__ rowmap,
                                                      const float* __restrict__ tw,
                                                      float* __restrict__ out) {
  int t = blockIdx.x;
  int h0 = threadIdx.x * 8;
  float acc[8] = {0.f, 0.f, 0.f, 0.f, 0.f, 0.f, 0.f, 0.f};
#pragma unroll
  for (int k = 0; k < KTOP; k++) {
    int r = rowmap[t * KTOP + k];
    float wt = tw[t * KTOP + k];
    u16x8 v = *(const u16x8*)(eo + (long)r * HDIM + h0);
#pragma unroll
    for (int j = 0; j < 8; j++)
      acc[j] += wt * __builtin_bit_cast(float, ((u32)v[j]) << 16);
  }
  float4 o0 = {acc[0], acc[1], acc[2], acc[3]};
  float4 o1 = {acc[4], acc[5], acc[6], acc[7]};
  *(float4*)(out + (long)t * HDIM + h0) = o0;
  *(float4*)(out + (long)t * HDIM + h0 + 4) = o1;
}

extern "C" void kernel_launch(void* const* d_in, const int* in_sizes, int n_in,
                              void* d_out, int out_size, void* d_ws, size_t ws_size,
                              hipStream_t stream) {
  const float* x = (const float*)d_in[0];
  const float* gw = (const float*)d_in[1];
  const float* wgate = (const float*)d_in[2];
  const float* wup = (const float*)d_in[3];
  const float* wdown = (const float*)d_in[4];
  float* out = (float*)d_out;

  char* ws = (char*)d_ws;
  u16* xb = (u16*)(ws + WS_XB);
  u16* act = (u16*)(ws + WS_ACT);
  int* tidx = (int*)(ws + WS_TIDX);
  float* tw = (float*)(ws + WS_TW);
  int* cnt = (int*)(ws + WS_CNT);
  int* offs = (int*)(ws + WS_OFFS);
  int* cur = (int*)(ws + WS_CUR);
  int* rtok = (int*)(ws + WS_RTOK);
  float* rw = (float*)(ws + WS_RW);
  int* rowmap = (int*)(ws + WS_RMAP);
  u16* eo = (u16*)(ws + WS_EO);
  bool storeMode = (ws_size >= (size_t)WS_NEED);

  hipMemsetAsync(cnt, 0, 128, stream);
  if (!storeMode)
    hipMemsetAsync(d_out, 0, (size_t)out_size * sizeof(float), stream);

  hipLaunchKernelGGL(router_kernel, dim3(TTOK), dim3(256), 0, stream, x, gw, xb, tidx, tw, cnt);
  hipLaunchKernelGGL(scan_kernel, dim3(1), dim3(64), 0, stream, cnt, offs, cur);
  hipLaunchKernelGGL(scatter_kernel, dim3(TTOK * KTOP / 256), dim3(256), 0, stream, tidx, tw, offs, cur, rtok, rw, rowmap);
  hipLaunchKernelGGL(gemm1_kernel, dim3(32 * 12 * 8), dim3(512), 0, stream, xb, wgate, wup, offs, rtok, act);
  if (storeMode) {
    hipLaunchKernelGGL(gemm2_kernel<1>, dim3(32 * 16 * 8), dim3(512), 0, stream, act, wdown, offs, rtok, rw, eo, out);
    hipLaunchKernelGGL(combine_kernel, dim3(TTOK), dim3(256), 0, stream, eo, rowmap, tw, out);
  } else {
    hipLaunchKernelGGL(gemm2_kernel<0>, dim3(32 * 16 * 8), dim3(512), 0, stream, act, wdown, offs, rtok, rw, eo, out);
  }
}